// Round 3
// baseline (227.423 us; speedup 1.0000x reference)
//
#include <hip/hip_runtime.h>

// Problem constants (fixed by reference setup_inputs).
#define N 32
#define T 64
#define C 256
#define L 64

// ---------------------------------------------------------------------------
// All-reduce sum across each 16-lane DPP row (VALU pipe only — no LDS/shfl).
// row_ror:8 (0x128), row_ror:4 (0x124), quad_perm(2,3,0,1)=0x4E (xor2),
// quad_perm(1,0,3,2)=0xB1 (xor1). After the 4 adds every lane of the 16-lane
// row holds the full sum.
// ---------------------------------------------------------------------------
__device__ __forceinline__ float dpp_allreduce16(float x) {
  int p;
  p = __builtin_amdgcn_update_dpp(0, __float_as_int(x), 0x128, 0xf, 0xf, false);
  x += __int_as_float(p);
  p = __builtin_amdgcn_update_dpp(0, __float_as_int(x), 0x124, 0xf, 0xf, false);
  x += __int_as_float(p);
  p = __builtin_amdgcn_update_dpp(0, __float_as_int(x), 0x4E, 0xf, 0xf, false);
  x += __int_as_float(p);
  p = __builtin_amdgcn_update_dpp(0, __float_as_int(x), 0xB1, 0xf, 0xf, false);
  x += __int_as_float(p);
  return x;
}

// ---------------------------------------------------------------------------
// Kernel 1: partial[t][n][l] = sum_c q[n,t,c,l] * k[t,n,c]
// Grid (T, N) = 2048 blocks x 256 threads (8 blocks/CU, 32 waves/CU).
// Block owns one t-row of q (64 KiB contiguous); k-row (1 KiB) staged in LDS.
// Quarter-wave owns one c per iteration; lane lq loads float4
// q[n,t,c,4lq..4lq+3] — the wave covers 1 KiB contiguous per instruction.
// ---------------------------------------------------------------------------
__global__ __launch_bounds__(256, 8) void scores_partial_kernel(
    const float* __restrict__ q, const float* __restrict__ k,
    float* __restrict__ partial) {
  const int t    = blockIdx.x;
  const int n    = blockIdx.y;
  const int tid  = threadIdx.x;
  const int lane = tid & 63;
  const int wave = tid >> 6;
  const int sub  = lane >> 4;
  const int lq   = lane & 15;
  const int g    = wave * 4 + sub;

  __shared__ float sk[C];
  __shared__ float sred[4 * L];

  sk[tid] = k[(t * N + n) * C + tid];   // tid == c, coalesced
  __syncthreads();

  const float* __restrict__ qrow = q + ((size_t)(n * T + t) * C) * L + lq * 4;

  float4 acc = make_float4(0.f, 0.f, 0.f, 0.f);
  #pragma unroll 8
  for (int c = g; c < C; c += 16) {     // 16 iterations
    const float4 qv = *reinterpret_cast<const float4*>(qrow + (size_t)c * L);
    const float kv = sk[c];             // LDS broadcast within quarter-wave
    acc.x = fmaf(qv.x, kv, acc.x);
    acc.y = fmaf(qv.y, kv, acc.y);
    acc.z = fmaf(qv.z, kv, acc.z);
    acc.w = fmaf(qv.w, kv, acc.w);
  }

  // Sum the 4 quarter-waves of this wave (same l-groups, different c's).
  acc.x += __shfl_xor(acc.x, 16); acc.y += __shfl_xor(acc.y, 16);
  acc.z += __shfl_xor(acc.z, 16); acc.w += __shfl_xor(acc.w, 16);
  acc.x += __shfl_xor(acc.x, 32); acc.y += __shfl_xor(acc.y, 32);
  acc.z += __shfl_xor(acc.z, 32); acc.w += __shfl_xor(acc.w, 32);

  if (lane < 16) {
    sred[wave * L + lq * 4 + 0] = acc.x;
    sred[wave * L + lq * 4 + 1] = acc.y;
    sred[wave * L + lq * 4 + 2] = acc.z;
    sred[wave * L + lq * 4 + 3] = acc.w;
  }
  __syncthreads();
  if (tid < L) {
    const float s = sred[tid] + sred[L + tid] + sred[2 * L + tid] + sred[3 * L + tid];
    partial[(size_t)t * (N * L) + n * L + tid] = s;
  }
}

// ---------------------------------------------------------------------------
// Kernel 1.5: probs[n][l] = softmax_l( sum_t partial[t][n][l] ).
// 32 blocks x 1 wave. Tiny (runs once, not 2048x in K2's prologue).
// ---------------------------------------------------------------------------
__global__ __launch_bounds__(64) void softmax_kernel(
    const float* __restrict__ partial, float* __restrict__ probs) {
  const int n = blockIdx.x;
  const int l = threadIdx.x;
  float s = 0.f;
  #pragma unroll
  for (int t = 0; t < T; ++t)
    s += partial[(size_t)t * (N * L) + n * L + l];   // coalesced 256 B each
  float m = s;
  #pragma unroll
  for (int off = 32; off > 0; off >>= 1) m = fmaxf(m, __shfl_xor(m, off));
  const float e = __expf(s - m);
  float z = e;
  #pragma unroll
  for (int off = 32; off > 0; off >>= 1) z += __shfl_xor(z, off);
  probs[n * L + l] = e / z;
}

// ---------------------------------------------------------------------------
// Kernel 2: out[t,n,c] = dot(q[n,t,c,:], probs[n,:]).
// Grid (T, N) x 256 threads. Fully-coalesced 1-KiB wave loads (quarter-wave
// per c, lane lq covers l = 4lq..4lq+3); 16-lane dot-reduce on the VALU via
// DPP (no LDS-pipe traffic). probs loaded once per thread (16 B, L2-hot).
// ---------------------------------------------------------------------------
__global__ __launch_bounds__(256, 8) void out_kernel(
    const float* __restrict__ q, const float* __restrict__ probs,
    float* __restrict__ out) {
  const int t    = blockIdx.x;
  const int n    = blockIdx.y;
  const int tid  = threadIdx.x;
  const int lane = tid & 63;
  const int wave = tid >> 6;
  const int sub  = lane >> 4;
  const int lq   = lane & 15;
  const int g    = wave * 4 + sub;

  const float4 pv = *reinterpret_cast<const float4*>(probs + n * L + lq * 4);
  const float* __restrict__ qrow = q + ((size_t)(n * T + t) * C) * L + lq * 4;
  float* __restrict__ orow = out + (size_t)(t * N + n) * C;

  #pragma unroll 8
  for (int c = g; c < C; c += 16) {     // 16 iterations
    const float4 qv = *reinterpret_cast<const float4*>(qrow + (size_t)c * L);
    float d = qv.x * pv.x + qv.y * pv.y + qv.z * pv.z + qv.w * pv.w;
    d = dpp_allreduce16(d);
    if (lq == 0) orow[c] = d;           // lanes 0/16/32/48: 16 B contiguous
  }
}

extern "C" void kernel_launch(void* const* d_in, const int* in_sizes, int n_in,
                              void* d_out, int out_size, void* d_ws, size_t ws_size,
                              hipStream_t stream) {
  const float* q = (const float*)d_in[0];   // query: (32,64,256,64) fp32
  const float* k = (const float*)d_in[1];   // key:   (64,32,256)    fp32
  float* out = (float*)d_out;               // out:   (64,32,256)    fp32
  float* partial = (float*)d_ws;            // [64][32][64] fp32 = 512 KiB
  float* probs   = partial + (size_t)T * N * L;  // [32][64] fp32 = 8 KiB

  dim3 grid(T, N);
  scores_partial_kernel<<<grid, 256, 0, stream>>>(q, k, partial);
  softmax_kernel<<<dim3(N), 64, 0, stream>>>(partial, probs);
  out_kernel<<<grid, 256, 0, stream>>>(q, probs, out);
}